// Round 2
// baseline (1080.854 us; speedup 1.0000x reference)
//
#include <hip/hip_runtime.h>
#include <math.h>

#define DMODEL 1024
#define NHEAD  16
#define DK     64
#define SEQ    2048
#define BATCH  2
#define MROWS  (BATCH * SEQ)   // 4096

// ---------------------------------------------------------------------------
// GEMM: C[M,N] = A[M,K] @ B[K,N], fp32 vector-ALU.
// BM=128, BN=64, BK=16, 256 threads, 8x4 micro-tile per thread.
// ---------------------------------------------------------------------------
__global__ __launch_bounds__(256)
void gemm128x64_f32(const float* __restrict__ A, const float* __restrict__ B,
                    float* __restrict__ C, int M, int N, int K)
{
    __shared__ float As[16][132];   // [kk][m], padded
    __shared__ float Bs[16][68];    // [kk][n], padded (68 = 4*17, float4-aligned)

    const int t  = threadIdx.x;
    const int bm = blockIdx.y * 128;
    const int bn = blockIdx.x * 64;
    const int ty = t >> 4;          // 0..15 -> output rows ty*8 .. +7
    const int tx = t & 15;          // 0..15 -> output cols tx*4 .. +3

    float acc[8][4];
#pragma unroll
    for (int i = 0; i < 8; ++i)
#pragma unroll
        for (int j = 0; j < 4; ++j) acc[i][j] = 0.0f;

    const int ar = t >> 2;          // A-load row 0..63 (+64 second pass)
    const int as = t & 3;           // A-load k-segment (float4)
    const int bk = t >> 4;          // B-load k row 0..15
    const int bs = t & 15;          // B-load n segment (float4)

    for (int k0 = 0; k0 < K; k0 += 16) {
        // A tile 128x16, transposed into As[kk][m]
#pragma unroll
        for (int p = 0; p < 2; ++p) {
            const int row = ar + p * 64;
            const float4 av = *(const float4*)(A + (size_t)(bm + row) * K + k0 + as * 4);
            As[as * 4 + 0][row] = av.x;
            As[as * 4 + 1][row] = av.y;
            As[as * 4 + 2][row] = av.z;
            As[as * 4 + 3][row] = av.w;
        }
        // B tile 16x64, natural layout
        {
            const float4 bv = *(const float4*)(B + (size_t)(k0 + bk) * N + bn + bs * 4);
            *(float4*)(&Bs[bk][bs * 4]) = bv;
        }
        __syncthreads();

#pragma unroll
        for (int kk = 0; kk < 16; ++kk) {
            const float4 a0 = *(const float4*)(&As[kk][ty * 8]);
            const float4 a1 = *(const float4*)(&As[kk][ty * 8 + 4]);
            const float4 b0 = *(const float4*)(&Bs[kk][tx * 4]);
            const float arr[8] = {a0.x, a0.y, a0.z, a0.w, a1.x, a1.y, a1.z, a1.w};
            const float brr[4] = {b0.x, b0.y, b0.z, b0.w};
#pragma unroll
            for (int i = 0; i < 8; ++i)
#pragma unroll
                for (int j = 0; j < 4; ++j)
                    acc[i][j] = fmaf(arr[i], brr[j], acc[i][j]);
        }
        __syncthreads();
    }

#pragma unroll
    for (int i = 0; i < 8; ++i) {
        const float4 cv = make_float4(acc[i][0], acc[i][1], acc[i][2], acc[i][3]);
        *(float4*)(C + (size_t)(bm + ty * 8 + i) * N + bn + tx * 4) = cv;
    }
}

// ---------------------------------------------------------------------------
// Flash attention, fp32. One block = one (b,h) x 64 q-rows. 256 threads,
// 16x16 thread grid, 4x4 micro-tile of the 64x64 score tile.
// K-tile LDS buffer (transposed) is reused as P^T after scores are consumed.
// ---------------------------------------------------------------------------
__global__ __launch_bounds__(256)
void flash_attn_f32(const float* __restrict__ QP, const float* __restrict__ KP,
                    const float* __restrict__ VP, const int* __restrict__ mask,
                    float* __restrict__ OUT)
{
    __shared__ float Qst[DK][68];   // [d][q-row], Q pre-scaled by 1/sqrt(dk)
    __shared__ float KPs[DK][68];   // K^T [d][k-col]; reused as P^T [k-col][q-row]
    __shared__ float Vs [DK][68];   // [k-row][d]

    const int t  = threadIdx.x;
    const int ty = t >> 4;          // 0..15 -> q rows ty*4 .. +3
    const int tx = t & 15;          // 0..15 -> k cols / d cols tx*4 .. +3
    const int bh = blockIdx.y;      // 0..31
    const int b  = bh >> 4;
    const int h  = bh & 15;
    const int q0 = blockIdx.x * 64;

    const float* qbase = QP + (size_t)b * SEQ * DMODEL + (size_t)h * DK;
    const float* kbase = KP + (size_t)b * SEQ * DMODEL + (size_t)h * DK;
    const float* vbase = VP + (size_t)b * SEQ * DMODEL + (size_t)h * DK;
    const int*   mbase = mask + (size_t)b * SEQ * SEQ;

    // stage Q tile (64 rows x 64 d), transposed + pre-scaled
#pragma unroll
    for (int p = 0; p < 4; ++p) {
        const int idx = t + p * 256;
        const int row = idx >> 4, seg = idx & 15;
        const float4 qv = *(const float4*)(qbase + (size_t)(q0 + row) * DMODEL + seg * 4);
        Qst[seg * 4 + 0][row] = qv.x * 0.125f;
        Qst[seg * 4 + 1][row] = qv.y * 0.125f;
        Qst[seg * 4 + 2][row] = qv.z * 0.125f;
        Qst[seg * 4 + 3][row] = qv.w * 0.125f;
    }

    float mrow[4], lrow[4], o[4][4];
#pragma unroll
    for (int i = 0; i < 4; ++i) {
        mrow[i] = -INFINITY;
        lrow[i] = 0.0f;
#pragma unroll
        for (int j = 0; j < 4; ++j) o[i][j] = 0.0f;
    }

    for (int kt = 0; kt < SEQ / 64; ++kt) {
        const int k0 = kt * 64;
        __syncthreads();   // previous iteration's P^T/V reads complete
        // stage K (transposed) and V (natural)
#pragma unroll
        for (int p = 0; p < 4; ++p) {
            const int idx = t + p * 256;
            const int row = idx >> 4, seg = idx & 15;
            const float4 kv = *(const float4*)(kbase + (size_t)(k0 + row) * DMODEL + seg * 4);
            KPs[seg * 4 + 0][row] = kv.x;
            KPs[seg * 4 + 1][row] = kv.y;
            KPs[seg * 4 + 2][row] = kv.z;
            KPs[seg * 4 + 3][row] = kv.w;
            const float4 vv = *(const float4*)(vbase + (size_t)(k0 + row) * DMODEL + seg * 4);
            *(float4*)(&Vs[row][seg * 4]) = vv;
        }
        __syncthreads();

        // scores 4x4 (Q pre-scaled)
        float s[4][4];
#pragma unroll
        for (int i = 0; i < 4; ++i)
#pragma unroll
            for (int j = 0; j < 4; ++j) s[i][j] = 0.0f;
        for (int d = 0; d < DK; ++d) {
            const float4 q4 = *(const float4*)(&Qst[d][ty * 4]);
            const float4 k4 = *(const float4*)(&KPs[d][tx * 4]);
            const float qa[4] = {q4.x, q4.y, q4.z, q4.w};
            const float kb[4] = {k4.x, k4.y, k4.z, k4.w};
#pragma unroll
            for (int i = 0; i < 4; ++i)
#pragma unroll
                for (int j = 0; j < 4; ++j)
                    s[i][j] = fmaf(qa[i], kb[j], s[i][j]);
        }

        // mask
#pragma unroll
        for (int i = 0; i < 4; ++i) {
            const int4 mv = *(const int4*)(mbase + (size_t)(q0 + ty * 4 + i) * SEQ + k0 + tx * 4);
            if (mv.x == 0) s[i][0] = -1e9f;
            if (mv.y == 0) s[i][1] = -1e9f;
            if (mv.z == 0) s[i][2] = -1e9f;
            if (mv.w == 0) s[i][3] = -1e9f;
        }

        // online softmax (row reduction across the 16 tx lanes of each ty group)
        float pr[4][4];
#pragma unroll
        for (int i = 0; i < 4; ++i) {
            float tm = fmaxf(fmaxf(s[i][0], s[i][1]), fmaxf(s[i][2], s[i][3]));
            tm = fmaxf(tm, __shfl_xor(tm, 1));
            tm = fmaxf(tm, __shfl_xor(tm, 2));
            tm = fmaxf(tm, __shfl_xor(tm, 4));
            tm = fmaxf(tm, __shfl_xor(tm, 8));
            const float mnew = fmaxf(mrow[i], tm);
            const float c = __expf(mrow[i] - mnew);
            mrow[i] = mnew;
            float r = 0.0f;
#pragma unroll
            for (int j = 0; j < 4; ++j) {
                pr[i][j] = __expf(s[i][j] - mnew);
                r += pr[i][j];
            }
            r += __shfl_xor(r, 1);
            r += __shfl_xor(r, 2);
            r += __shfl_xor(r, 4);
            r += __shfl_xor(r, 8);
            lrow[i] = lrow[i] * c + r;
#pragma unroll
            for (int j = 0; j < 4; ++j) o[i][j] *= c;
        }

        __syncthreads();   // everyone done reading KPs as K
        // write P^T into KPs
#pragma unroll
        for (int i = 0; i < 4; ++i)
#pragma unroll
            for (int j = 0; j < 4; ++j)
                KPs[tx * 4 + j][ty * 4 + i] = pr[i][j];
        __syncthreads();

        // O += P @ V   (rows ty*4.., d-cols tx*4..)
        for (int jj = 0; jj < 64; ++jj) {
            const float4 p4 = *(const float4*)(&KPs[jj][ty * 4]);
            const float4 v4 = *(const float4*)(&Vs[jj][tx * 4]);
            const float pa[4] = {p4.x, p4.y, p4.z, p4.w};
            const float vb[4] = {v4.x, v4.y, v4.z, v4.w};
#pragma unroll
            for (int i = 0; i < 4; ++i)
#pragma unroll
                for (int j = 0; j < 4; ++j)
                    o[i][j] = fmaf(pa[i], vb[j], o[i][j]);
        }
    }

    // epilogue: normalize and write [B,S,DMODEL] (heads concatenated)
    float* obase = OUT + (size_t)b * SEQ * DMODEL + (size_t)h * DK;
#pragma unroll
    for (int i = 0; i < 4; ++i) {
        const float inv = 1.0f / lrow[i];
        const float4 ov = make_float4(o[i][0] * inv, o[i][1] * inv,
                                      o[i][2] * inv, o[i][3] * inv);
        *(float4*)(obase + (size_t)(q0 + ty * 4 + i) * DMODEL + tx * 4) = ov;
    }
}

// ---------------------------------------------------------------------------
extern "C" void kernel_launch(void* const* d_in, const int* in_sizes, int n_in,
                              void* d_out, int out_size, void* d_ws, size_t ws_size,
                              hipStream_t stream)
{
    const float* q    = (const float*)d_in[0];
    const float* k    = (const float*)d_in[1];
    const float* v    = (const float*)d_in[2];
    const int*   mask = (const int*)  d_in[3];
    const float* w_q  = (const float*)d_in[4];
    const float* w_k  = (const float*)d_in[5];
    const float* w_v  = (const float*)d_in[6];
    const float* w_o  = (const float*)d_in[7];
    float*       out  = (float*)d_out;

    const size_t proj_elems = (size_t)MROWS * DMODEL;   // 4096*1024 fp32 = 16 MB
    float* qp = (float*)d_ws;
    float* kp = qp + proj_elems;
    float* vp = kp + proj_elems;
    float* ao = vp + proj_elems;                        // total 64 MB of ws

    const dim3 blk(256);
    const dim3 ggrid(DMODEL / 64, MROWS / 128);         // (16, 32)

    gemm128x64_f32<<<ggrid, blk, 0, stream>>>(q, w_q, qp, MROWS, DMODEL, DMODEL);
    gemm128x64_f32<<<ggrid, blk, 0, stream>>>(k, w_k, kp, MROWS, DMODEL, DMODEL);
    gemm128x64_f32<<<ggrid, blk, 0, stream>>>(v, w_v, vp, MROWS, DMODEL, DMODEL);

    const dim3 agrid(SEQ / 64, BATCH * NHEAD);          // (32, 32)
    flash_attn_f32<<<agrid, blk, 0, stream>>>(qp, kp, vp, mask, ao);

    gemm128x64_f32<<<ggrid, blk, 0, stream>>>(ao, w_o, out, MROWS, DMODEL, DMODEL);
}

// Round 3
// 409.403 us; speedup vs baseline: 2.6401x; 2.6401x over previous
//
#include <hip/hip_runtime.h>
#include <math.h>
#include <stdint.h>

#define DMODEL 1024
#define NHEAD  16
#define DK     64
#define SEQ    2048
#define BATCH  2
#define MROWS  (BATCH * SEQ)   // 4096

typedef __attribute__((ext_vector_type(4))) float f32x4;
typedef __attribute__((ext_vector_type(8))) unsigned short u16x8;
typedef __attribute__((ext_vector_type(4))) unsigned short u16x4;

// fp32 -> bf16 round-to-nearest-even (inputs are finite; no NaN handling needed)
__device__ __forceinline__ unsigned short f2bf(float f) {
    union { float f; uint32_t u; } v; v.f = f;
    uint32_t u = v.u;
    u += 0x7FFFu + ((u >> 16) & 1u);
    return (unsigned short)(u >> 16);
}

// MFMA via inline asm: avoids builtin signature ambiguity (short8 vs __bf16 x8).
// D/C tied ("+v"); A,B are 4-VGPR groups. Accumulator chains are HW-interlocked.
__device__ __forceinline__ f32x4 mfma16x16x32(u16x8 a, u16x8 b, f32x4 c) {
    asm("v_mfma_f32_16x16x32_bf16 %0, %1, %2, %0" : "+v"(c) : "v"(a), "v"(b));
    return c;
}

typedef __attribute__((address_space(3))) unsigned int lds_u32;
typedef __attribute__((address_space(1))) unsigned int glb_u32;
__device__ __forceinline__ void gload16(const void* g, void* l) {
    __builtin_amdgcn_global_load_lds((const glb_u32*)g, (lds_u32*)l, 16, 0, 0);
}

// ---------------------------------------------------------------------------
// Weight transpose+convert: W[k][n] f32 -> Wt[n][k] bf16. 64x64 tiles via LDS.
// ---------------------------------------------------------------------------
__global__ __launch_bounds__(256)
void transpose_w(const float* __restrict__ W, unsigned short* __restrict__ Wt)
{
    __shared__ unsigned short T[64 * 72];   // [n][k], stride 72 breaks pow2
    const int t = threadIdx.x;
    const int n0 = blockIdx.x * 64, k0 = blockIdx.y * 64;
#pragma unroll
    for (int p = 0; p < 4; ++p) {
        int s = t + p * 256;
        int kr = s >> 4, f4 = s & 15;
        float4 wv = *(const float4*)(W + (size_t)(k0 + kr) * DMODEL + n0 + f4 * 4);
        T[(f4 * 4 + 0) * 72 + kr] = f2bf(wv.x);
        T[(f4 * 4 + 1) * 72 + kr] = f2bf(wv.y);
        T[(f4 * 4 + 2) * 72 + kr] = f2bf(wv.z);
        T[(f4 * 4 + 3) * 72 + kr] = f2bf(wv.w);
    }
    __syncthreads();
#pragma unroll
    for (int p = 0; p < 2; ++p) {
        int s = t + p * 256;
        int n = s >> 3, kc = s & 7;
        u16x8 v = *(const u16x8*)(&T[n * 72 + kc * 8]);
        *(u16x8*)(Wt + (size_t)(n0 + n) * DMODEL + k0 + kc * 8) = v;
    }
}

// ---------------------------------------------------------------------------
// GEMM C[4096,1024] = A[4096,1024] @ Wt^T, MFMA bf16, BM=64 BN=128 BK=32.
// A_F32: A is fp32 (reg-stage + convert); else bf16 (global_load_lds).
// OMODE 0: C bf16 [m][n]; 1: C bf16 transposed per batch [b][n][s]; 2: C f32.
// LDS XOR swizzle: 16B unit col c of row r lives at slot c^(r&3) (4 cols/row).
// ---------------------------------------------------------------------------
template<int A_F32, int OMODE>
__global__ __launch_bounds__(256)
void gemm_mfma(const void* __restrict__ Ap, const unsigned short* __restrict__ Bt,
               void* __restrict__ Cp)
{
    __shared__ unsigned short As[64 * 32];    // 4 KB
    __shared__ unsigned short Bs[128 * 32];   // 8 KB
    const int t = threadIdx.x, w = t >> 6, lane = t & 63;
    const int l15 = lane & 15, g = lane >> 4;
    const int bn = blockIdx.x * 128, bm = blockIdx.y * 64;
    const int wr = w >> 1, wc = w & 1;        // wave sub-tile 32x64

    f32x4 acc[2][4];
#pragma unroll
    for (int i = 0; i < 2; ++i)
#pragma unroll
        for (int j = 0; j < 4; ++j) acc[i][j] = (f32x4){0.f, 0.f, 0.f, 0.f};

    for (int k0 = 0; k0 < DMODEL; k0 += 32) {
        __syncthreads();                      // prior tile reads complete
        if (A_F32) {
            const float* A = (const float*)Ap;
#pragma unroll
            for (int p = 0; p < 2; ++p) {
                int seg = t + p * 256;        // 512 segs of 4 f32
                int row = seg >> 3, f4 = seg & 7;
                float4 av = *(const float4*)(A + (size_t)(bm + row) * DMODEL + k0 + f4 * 4);
                u16x4 bv = { f2bf(av.x), f2bf(av.y), f2bf(av.z), f2bf(av.w) };
                *(u16x4*)((char*)As + row * 64 + (((f4 >> 1) ^ (row & 3)) * 16) + (f4 & 1) * 8) = bv;
            }
        } else {
            const unsigned short* A = (const unsigned short*)Ap;
            int row = t >> 2, c = t & 3;      // 256 segs of 16B
            gload16(A + (size_t)(bm + row) * DMODEL + k0 + ((c ^ (row & 3)) * 8),
                    (char*)As + t * 16);
        }
#pragma unroll
        for (int rnd = 0; rnd < 2; ++rnd) {   // B: 512 segs of 16B
            int seg = w * 64 + rnd * 256 + lane;
            int row = seg >> 2, c = seg & 3;
            gload16(Bt + (size_t)(bn + row) * DMODEL + k0 + ((c ^ (row & 3)) * 8),
                    (char*)Bs + seg * 16);
        }
        asm volatile("s_waitcnt vmcnt(0)" ::: "memory");
        __syncthreads();

        u16x8 af[2], bfr[4];
#pragma unroll
        for (int mi = 0; mi < 2; ++mi) {
            int row = wr * 32 + mi * 16 + l15;
            af[mi] = *(const u16x8*)((const char*)As + row * 64 + ((g ^ (row & 3)) * 16));
        }
#pragma unroll
        for (int nj = 0; nj < 4; ++nj) {
            int row = wc * 64 + nj * 16 + l15;
            bfr[nj] = *(const u16x8*)((const char*)Bs + row * 64 + ((g ^ (row & 3)) * 16));
        }
#pragma unroll
        for (int mi = 0; mi < 2; ++mi)
#pragma unroll
            for (int nj = 0; nj < 4; ++nj)
                acc[mi][nj] = mfma16x16x32(af[mi], bfr[nj], acc[mi][nj]);
    }

#pragma unroll
    for (int mi = 0; mi < 2; ++mi)
#pragma unroll
        for (int nj = 0; nj < 4; ++nj) {
            int n  = bn + wc * 64 + nj * 16 + l15;
            int m0 = bm + wr * 32 + mi * 16 + g * 4;
            if (OMODE == 0) {
                unsigned short* C = (unsigned short*)Cp;
#pragma unroll
                for (int r = 0; r < 4; ++r)
                    C[(size_t)(m0 + r) * DMODEL + n] = f2bf(acc[mi][nj][r]);
            } else if (OMODE == 1) {          // V: [b][n][s]
                unsigned short* C = (unsigned short*)Cp;
                int bb = m0 >> 11, s0 = m0 & 2047;
                u16x4 pv = { f2bf(acc[mi][nj][0]), f2bf(acc[mi][nj][1]),
                             f2bf(acc[mi][nj][2]), f2bf(acc[mi][nj][3]) };
                *(u16x4*)(C + (size_t)bb * DMODEL * SEQ + (size_t)n * SEQ + s0) = pv;
            } else {
                float* C = (float*)Cp;
#pragma unroll
                for (int r = 0; r < 4; ++r)
                    C[(size_t)(m0 + r) * DMODEL + n] = acc[mi][nj][r];
            }
        }
}

// ---------------------------------------------------------------------------
// Flash attention, bf16 MFMA. Block = (b,h) x 64 q-rows; 4 waves x 16 q-rows.
// K_lds/V_lds/Q_lds 64x64 bf16, XOR-swizzled (col16 ^= row&7, 8 cols/row).
// Q_lds reused as P_lds (per-wave-private region -> no cross-wave barrier).
// ---------------------------------------------------------------------------
__global__ __launch_bounds__(256)
void attn_mfma(const unsigned short* __restrict__ Qp, const unsigned short* __restrict__ Kp,
               const unsigned short* __restrict__ Vt, const int* __restrict__ mask,
               unsigned short* __restrict__ AO)
{
    __shared__ unsigned short Kl[64 * 64];
    __shared__ unsigned short Vl[64 * 64];
    __shared__ unsigned short Ql[64 * 64];

    const int t = threadIdx.x, w = t >> 6, lane = t & 63;
    const int l15 = lane & 15, g = lane >> 4;
    const int bh = blockIdx.y, b = bh >> 4, h = bh & 15;
    const int q0 = blockIdx.x * 64;

    const size_t bsd = (size_t)b * SEQ * DMODEL;
    const unsigned short* Qb = Qp + bsd + (size_t)q0 * DMODEL + h * 64;
    const unsigned short* Kb = Kp + bsd + h * 64;
    const unsigned short* Vb = Vt + (size_t)b * DMODEL * SEQ + (size_t)(h * 64) * SEQ;
    const int* mb = mask + (size_t)b * SEQ * SEQ;

    // stage Q (pre-swizzled source -> linear LDS dest)
#pragma unroll
    for (int rnd = 0; rnd < 2; ++rnd) {
        int seg = w * 64 + rnd * 256 + lane;
        int row = seg >> 3, c = seg & 7;
        gload16(Qb + (size_t)row * DMODEL + ((c ^ (row & 7)) * 8), (char*)Ql + seg * 16);
    }
    asm volatile("s_waitcnt vmcnt(0)" ::: "memory");
    __syncthreads();

    u16x8 qf[2];                              // hoisted Q A-frags
    {
        int qrow = w * 16 + l15;
#pragma unroll
        for (int ks = 0; ks < 2; ++ks)
            qf[ks] = *(const u16x8*)((const char*)Ql + qrow * 128 +
                                     (((ks * 4 + g) ^ (qrow & 7)) * 16));
    }
    __syncthreads();

    f32x4 o[4];
    f32x4 s[4];
    float mrow[4], lrow[4];
#pragma unroll
    for (int i = 0; i < 4; ++i) {
        o[i] = (f32x4){0.f, 0.f, 0.f, 0.f};
        s[i] = (f32x4){0.f, 0.f, 0.f, 0.f};
        mrow[i] = -INFINITY; lrow[i] = 0.f;
    }

    for (int kt = 0; kt < SEQ / 64; ++kt) {
        const int k0 = kt * 64;
        __syncthreads();                      // prev tile reads complete
#pragma unroll
        for (int rnd = 0; rnd < 2; ++rnd) {
            int seg = w * 64 + rnd * 256 + lane;
            int row = seg >> 3, c = seg & 7;
            gload16(Kb + (size_t)(k0 + row) * DMODEL + ((c ^ (row & 7)) * 8), (char*)Kl + seg * 16);
            gload16(Vb + (size_t)row * SEQ + k0 + ((c ^ (row & 7)) * 8), (char*)Vl + seg * 16);
        }
        asm volatile("s_waitcnt vmcnt(0)" ::: "memory");
        __syncthreads();

        // S = Q K^T (f: kv frag, ks: k-step). s[] zeroed far upstream.
#pragma unroll
        for (int f = 0; f < 4; ++f) {
            int krow = f * 16 + l15;
#pragma unroll
            for (int ks = 0; ks < 2; ++ks) {
                u16x8 kf = *(const u16x8*)((const char*)Kl + krow * 128 +
                                           (((ks * 4 + g) ^ (krow & 7)) * 16));
                s[f] = mfma16x16x32(qf[ks], kf, s[f]);
            }
        }

        // scale (1/sqrt(64)) + mask
        const int qrb = q0 + w * 16 + g * 4;
#pragma unroll
        for (int f = 0; f < 4; ++f) {
            const int kvg = k0 + f * 16 + l15;
#pragma unroll
            for (int r = 0; r < 4; ++r) {
                float sv = s[f][r] * 0.125f;
                s[f][r] = (mb[(size_t)(qrb + r) * SEQ + kvg] == 0) ? -1e9f : sv;
            }
        }

        // online softmax per q-row (reduce across 16 lanes of the l15 group)
#pragma unroll
        for (int r = 0; r < 4; ++r) {
            float tm = fmaxf(fmaxf(s[0][r], s[1][r]), fmaxf(s[2][r], s[3][r]));
            tm = fmaxf(tm, __shfl_xor(tm, 1));
            tm = fmaxf(tm, __shfl_xor(tm, 2));
            tm = fmaxf(tm, __shfl_xor(tm, 4));
            tm = fmaxf(tm, __shfl_xor(tm, 8));
            float mn = fmaxf(mrow[r], tm);
            float cc = __expf(mrow[r] - mn);
            mrow[r] = mn;
            float rs = 0.f;
#pragma unroll
            for (int f = 0; f < 4; ++f) {
                float p = __expf(s[f][r] - mn);
                s[f][r] = p;
                rs += p;
            }
            rs += __shfl_xor(rs, 1);
            rs += __shfl_xor(rs, 2);
            rs += __shfl_xor(rs, 4);
            rs += __shfl_xor(rs, 8);
            lrow[r] = lrow[r] * cc + rs;
#pragma unroll
            for (int nj = 0; nj < 4; ++nj) o[nj][r] *= cc;
        }

        // P (C-layout) -> swizzled P_lds (=Ql, per-wave-private rows)
#pragma unroll
        for (int f = 0; f < 4; ++f) {
            int kv = f * 16 + l15;
            int c16 = kv >> 3, cl = kv & 7;
#pragma unroll
            for (int r = 0; r < 4; ++r) {
                int q = w * 16 + g * 4 + r;
                *(unsigned short*)((char*)Ql + q * 128 + ((c16 ^ (q & 7)) * 16) + cl * 2) = f2bf(s[f][r]);
            }
        }

        // P A-frags back; zero s[] for next tile while LDS settles
        u16x8 pf[2];
        {
            int q = w * 16 + l15;
#pragma unroll
            for (int ks = 0; ks < 2; ++ks)
                pf[ks] = *(const u16x8*)((const char*)Ql + q * 128 +
                                         (((ks * 4 + g) ^ (q & 7)) * 16));
        }
#pragma unroll
        for (int i = 0; i < 4; ++i) s[i] = (f32x4){0.f, 0.f, 0.f, 0.f};

        // O += P V
#pragma unroll
        for (int nj = 0; nj < 4; ++nj) {
            int dr = nj * 16 + l15;
#pragma unroll
            for (int ks = 0; ks < 2; ++ks) {
                u16x8 vf = *(const u16x8*)((const char*)Vl + dr * 128 +
                                           (((ks * 4 + g) ^ (dr & 7)) * 16));
                o[nj] = mfma16x16x32(pf[ks], vf, o[nj]);
            }
        }
    }

    unsigned short* aob = AO + bsd + h * 64;
#pragma unroll
    for (int r = 0; r < 4; ++r) {
        float inv = 1.f / lrow[r];
        int qg = q0 + w * 16 + g * 4 + r;
#pragma unroll
        for (int nj = 0; nj < 4; ++nj)
            aob[(size_t)qg * DMODEL + nj * 16 + l15] = f2bf(o[nj][r] * inv);
    }
}

// ---------------------------------------------------------------------------
extern "C" void kernel_launch(void* const* d_in, const int* in_sizes, int n_in,
                              void* d_out, int out_size, void* d_ws, size_t ws_size,
                              hipStream_t stream)
{
    const float* q   = (const float*)d_in[0];
    const float* k   = (const float*)d_in[1];
    const float* v   = (const float*)d_in[2];
    const int*   mask= (const int*)  d_in[3];
    const float* w_q = (const float*)d_in[4];
    const float* w_k = (const float*)d_in[5];
    const float* w_v = (const float*)d_in[6];
    const float* w_o = (const float*)d_in[7];
    float*       out = (float*)d_out;

    unsigned short* ws = (unsigned short*)d_ws;
    const size_t WSZ = (size_t)DMODEL * DMODEL;   // 1M elems
    const size_t PSZ = (size_t)MROWS * DMODEL;    // 4M elems
    unsigned short* Wtq = ws;
    unsigned short* Wtk = Wtq + WSZ;
    unsigned short* Wtv = Wtk + WSZ;
    unsigned short* Wto = Wtv + WSZ;
    unsigned short* Qp  = Wto + WSZ;
    unsigned short* Kp  = Qp + PSZ;
    unsigned short* Vtp = Kp + PSZ;
    unsigned short* AO  = Vtp + PSZ;              // total 40 MB

    dim3 blk(256);
    dim3 tgrid(16, 16);
    transpose_w<<<tgrid, blk, 0, stream>>>(w_q, Wtq);
    transpose_w<<<tgrid, blk, 0, stream>>>(w_k, Wtk);
    transpose_w<<<tgrid, blk, 0, stream>>>(w_v, Wtv);
    transpose_w<<<tgrid, blk, 0, stream>>>(w_o, Wto);

    dim3 ggrid(DMODEL / 128, MROWS / 64);         // (8, 64) = 512 blocks
    gemm_mfma<1, 0><<<ggrid, blk, 0, stream>>>(q, Wtq, Qp);
    gemm_mfma<1, 0><<<ggrid, blk, 0, stream>>>(k, Wtk, Kp);
    gemm_mfma<1, 1><<<ggrid, blk, 0, stream>>>(v, Wtv, Vtp);

    dim3 agrid(SEQ / 64, BATCH * NHEAD);          // (32, 32)
    attn_mfma<<<agrid, blk, 0, stream>>>(Qp, Kp, Vtp, mask, AO);

    gemm_mfma<0, 2><<<ggrid, blk, 0, stream>>>(AO, Wto, out);
}